// Round 2
// baseline (418.702 us; speedup 1.0000x reference)
//
#include <hip/hip_runtime.h>

// RoPE, revolution-unit hardware transcendentals.
// out[...,2k]   = cos(a_k)*x[2k] - sin(a_k)*x[2k+1]
// out[...,2k+1] = sin(a_k)*x[2k] + cos(a_k)*x[2k+1]
// a_k = pos * 10000^(-k/64) rad, k in [0,64), rows = 4*32*4096, D=128.
//
// Angle in revolutions: a_rev = pos * exp2(k*C + L), C = -log2(10000)/64,
// L = log2(1/(2*pi)). Then v_fract + v_sin/v_cos (D = sin(S0*2pi)).
// One thread per float4 (2 pairs, 16 B/lane coalesced).

#define BLOCK 256

__global__ __launch_bounds__(BLOCK) void rope_kernel(
    const float4* __restrict__ x,
    const int* __restrict__ pos,
    float4* __restrict__ out,
    int n_f4)
{
    int tid = blockIdx.x * BLOCK + threadIdx.x;
    if (tid >= n_f4) return;

    int row = tid >> 5;        // 32 float4 per row of 128
    int j   = tid & 31;        // float4 index within row -> pairs 2j, 2j+1

    float p = (float)pos[row]; // broadcast load for 32 consecutive lanes
    float4 v = x[tid];

    const float C = -0.2076205059304601f;   // -log2(10000)/64
    const float L = -2.6514961294723187f;   // log2(1/(2*pi))

    float k0 = (float)(2 * j);
    // angle in revolutions
    float a0 = p * __builtin_amdgcn_exp2f(fmaf(k0, C, L));
    float a1 = p * __builtin_amdgcn_exp2f(fmaf(k0 + 1.0f, C, L));

    float r0 = __builtin_amdgcn_fractf(a0);
    float r1 = __builtin_amdgcn_fractf(a1);

    float s0 = __builtin_amdgcn_sinf(r0);   // sin(r0 * 2pi)
    float c0 = __builtin_amdgcn_cosf(r0);
    float s1 = __builtin_amdgcn_sinf(r1);
    float c1 = __builtin_amdgcn_cosf(r1);

    float4 r;
    r.x = c0 * v.x - s0 * v.y;
    r.y = s0 * v.x + c0 * v.y;
    r.z = c1 * v.z - s1 * v.w;
    r.w = s1 * v.z + c1 * v.w;
    out[tid] = r;
}

extern "C" void kernel_launch(void* const* d_in, const int* in_sizes, int n_in,
                              void* d_out, int out_size, void* d_ws, size_t ws_size,
                              hipStream_t stream) {
    const float4* x  = (const float4*)d_in[0];
    const int* pos   = (const int*)d_in[1];
    float4* out      = (float4*)d_out;

    int n_f4 = out_size / 4;               // 16,777,216
    int blocks = (n_f4 + BLOCK - 1) / BLOCK;
    rope_kernel<<<blocks, BLOCK, 0, stream>>>(x, pos, out, n_f4);
}